// Round 3
// baseline (1305.430 us; speedup 1.0000x reference)
//
#include <hip/hip_runtime.h>

typedef unsigned short u16;
typedef unsigned int u32;
typedef unsigned long long u64;
typedef __attribute__((ext_vector_type(8))) short short8;
typedef __attribute__((ext_vector_type(4))) float f32x4;

#define N_ELEM 8388608
#define NH 32
#define SEQ 2048
#define HD 128
#define KTOP 32768u
#define CAND_CAP 8192u

__device__ __forceinline__ u16 f2bf(float f) {
  union { float f; u32 u; } v; v.f = f;
  u32 r = v.u + 0x7fffu + ((v.u >> 16) & 1u);
  return (u16)(r >> 16);
}

// fp32 quant-dequant, exact reference semantics; keeps outliers & sinks verbatim
__device__ __forceinline__ float dqf(float x, u32 t, u64 Kr, u32 idx, bool sink, float scale) {
  union { float f; u32 u; } w; w.f = x;
  const u32 ab = w.u & 0x7fffffffu;
  const u32 bin = ab >> 16;
  const bool keep = sink || (bin > t) ||
                    (bin == t && ((((u64)ab) << 32) | (u32)(~idx)) >= Kr);
  if (keep) return x;
  float q = rintf(x / scale);            // round-half-even == jnp.round
  q = fminf(fmaxf(q, -8.0f), 7.0f);
  return q * scale;
}

// ---------------- K1: 32768-bin histogram of fp32 abs-bits>>16 ----------------
// 128 blocks x 256 thr; [0,64)->K, [64,128)->V. 64KB LDS = 32768 packed u16 bins.
__global__ __launch_bounds__(256) void hist_kernel(const float* __restrict__ k,
                                                   const float* __restrict__ v,
                                                   u32* __restrict__ histK,
                                                   u32* __restrict__ histV) {
  __shared__ u32 sh[16384];
  const int tensor = blockIdx.x >> 6;
  const int bid = blockIdx.x & 63;
  const float* src = tensor ? v : k;
  u32* gh = tensor ? histV : histK;
  for (int i = threadIdx.x; i < 16384; i += 256) sh[i] = 0;
  __syncthreads();
  const int per = N_ELEM / 64;  // 131072
  const int base = bid * per;
  for (int i = threadIdx.x; i < per / 4; i += 256) {
    f32x4 x = *(const f32x4*)(src + base + i * 4);
#pragma unroll
    for (int j = 0; j < 4; ++j) {
      union { float f; u32 u; } w; w.f = x[j];
      u32 b = (w.u & 0x7fffffffu) >> 16;
      atomicAdd(&sh[b >> 1], 1u << ((b & 1u) * 16));
    }
  }
  __syncthreads();
  for (int i = threadIdx.x; i < 16384; i += 256) {
    u32 w = sh[i];
    u32 lo = w & 0xffffu, hi = w >> 16;
    if (lo) atomicAdd(&gh[2 * i], lo);
    if (hi) atomicAdd(&gh[2 * i + 1], hi);
  }
}

// ---------------- K2: threshold bin t + tie budget r ----------------
// ctrl per tensor (8 u32): [t, r, KrHi, KrLo, candCount, -, -, -]
__global__ __launch_bounds__(256) void thresh_kernel(const u32* __restrict__ histK,
                                                     const u32* __restrict__ histV,
                                                     u32* __restrict__ ctrl) {
  const u32* hist = blockIdx.x ? histV : histK;
  u32* c = ctrl + blockIdx.x * 8;
  __shared__ u32 part[256];
  u32 s = 0;
  for (int i = 0; i < 128; ++i) s += hist[threadIdx.x * 128 + i];
  part[threadIdx.x] = s;
  __syncthreads();
  if (threadIdx.x == 0) {
    u32 cum = 0;
    int chunk = 255;
    while (chunk > 0 && cum + part[chunk] < KTOP) { cum += part[chunk]; --chunk; }
    int b = chunk * 128 + 127;
    while (b > 0 && cum + hist[b] < KTOP) { cum += hist[b]; --b; }
    c[0] = (u32)b;       // threshold bin
    c[1] = KTOP - cum;   // r elements to take from bin t (largest key first)
  }
}

// ---------------- K3: gather candidates in bin t (abs bits + flat idx) --------------
__global__ __launch_bounds__(256) void cand_kernel(const float* __restrict__ k,
                                                   const float* __restrict__ v,
                                                   u32* __restrict__ ctrl,
                                                   u32* __restrict__ caK, u32* __restrict__ ciK,
                                                   u32* __restrict__ caV, u32* __restrict__ ciV) {
  const int tensor = blockIdx.y;
  const float* src = tensor ? v : k;
  const u32 t = ctrl[tensor * 8 + 0];
  u32* ca = tensor ? caV : caK;
  u32* ci = tensor ? ciV : ciK;
  u32* cnt = &ctrl[tensor * 8 + 4];
  const int stride = gridDim.x * 256;
  for (int i = blockIdx.x * 256 + threadIdx.x; i < N_ELEM / 4; i += stride) {
    f32x4 x = *(const f32x4*)(src + i * 4);
#pragma unroll
    for (int j = 0; j < 4; ++j) {
      union { float f; u32 u; } w; w.f = x[j];
      const u32 ab = w.u & 0x7fffffffu;
      if ((ab >> 16) == t) {
        u32 slot = atomicAdd(cnt, 1u);
        if (slot < CAND_CAP) { ca[slot] = ab; ci[slot] = (u32)(i * 4 + j); }
      }
    }
  }
}

// ---------------- K4: find Kr = r-th largest key among candidates ----------------
// key = (abs_bits<<32) | ~idx  (larger |x| wins; equal |x| -> smaller idx wins)
__global__ __launch_bounds__(256) void ksel_kernel(u32* __restrict__ ctrl,
                                                   const u32* __restrict__ caK, const u32* __restrict__ ciK,
                                                   const u32* __restrict__ caV, const u32* __restrict__ ciV) {
  const int tensor = blockIdx.x;
  u32* c = ctrl + tensor * 8;
  const u32 r = c[1];
  u32 T = c[4];
  if (T > CAND_CAP) T = CAND_CAP;
  const u32* ca = tensor ? caV : caK;
  const u32* ci = tensor ? ciV : ciK;
  for (u32 i = threadIdx.x; i < T; i += 256) {
    const u64 ki = (((u64)ca[i]) << 32) | (u32)(~ci[i]);
    u32 cnt = 0;
    for (u32 j = 0; j < T; ++j) {
      const u64 kj = (((u64)ca[j]) << 32) | (u32)(~ci[j]);
      cnt += (kj > ki) ? 1u : 0u;
    }
    if (cnt == r - 1) { c[2] = (u32)(ki >> 32); c[3] = (u32)ki; }  // exactly one writer
  }
}

// ---------------- K5: per-(h,d) max|x| over non-outlier (non-sink for V) ------------
__global__ __launch_bounds__(128) void maxabs_kernel(const float* __restrict__ k,
                                                     const float* __restrict__ v,
                                                     const u32* __restrict__ ctrl,
                                                     u32* __restrict__ kmax,
                                                     u32* __restrict__ vmax) {
  const int h = blockIdx.x, sc = blockIdx.y, tensor = blockIdx.z;
  const float* src = tensor ? v : k;
  const u32* c = ctrl + tensor * 8;
  const u32 t = c[0];
  const u64 Kr = (((u64)c[2]) << 32) | c[3];
  u32* mbuf = tensor ? vmax : kmax;
  const int d = threadIdx.x;
  u32 mx = 0;
  for (int si = 0; si < 128; ++si) {
    const int s = sc * 128 + si;
    if (tensor == 1 && s < 4) continue;          // V sinks excluded from scale
    const u32 idx = ((u32)(h * SEQ + s) << 7) + (u32)d;
    union { float f; u32 u; } w; w.f = src[idx];
    const u32 ab = w.u & 0x7fffffffu;
    const u32 bin = ab >> 16;
    const bool outl = (bin > t) ||
                      (bin == t && ((((u64)ab) << 32) | (u32)(~idx)) >= Kr);
    if (!outl && ab > mx) mx = ab;
  }
  atomicMax(&mbuf[h * HD + d], mx);
}

// ---------------- K6: scales: max(|.|,eps)/7 in fp32 ----------------
__global__ __launch_bounds__(256) void scale_kernel(const u32* __restrict__ kmax,
                                                    const u32* __restrict__ vmax,
                                                    float* __restrict__ kscale,
                                                    float* __restrict__ vscale) {
  const int i = blockIdx.x * 256 + threadIdx.x;
  if (i < NH * HD) {
    union { u32 u; float f; } a, b;
    a.u = kmax[i]; b.u = vmax[i];
    kscale[i] = fmaxf(a.f, 1e-6f) / 7.0f;
    vscale[i] = fmaxf(b.f, 1e-6f) / 7.0f;
  }
}

// ---------------- K7: causal flash attention, inline fp32 quant-dequant -> bf16 MFMA
__global__ __launch_bounds__(256, 2) void flash_kernel(const float* __restrict__ Q,
                                                       const float* __restrict__ K,
                                                       const float* __restrict__ V,
                                                       const u32* __restrict__ ctrl,
                                                       const float* __restrict__ kscale,
                                                       const float* __restrict__ vscale,
                                                       float* __restrict__ Out) {
  __shared__ u16 ks[64][136];     // K tile (token x channel) bf16, pad 128->136
  __shared__ u16 vt[128][72];     // V^T tile (channel x token) bf16, pad 64->72
  __shared__ u16 pl[4][16][72];   // per-wave P tile (qrow x token), pad 64->72

  const int blk = blockIdx.x;
  const int h = blk >> 5;
  const int qt = 31 - (blk & 31);  // longest k-loops dispatched first
  const int qb = qt << 6;
  const int tid = threadIdx.x;
  const int w = tid >> 6, lane = tid & 63;
  const int l16 = lane & 15, quad = lane >> 4;
  const float SM_SCALE = 0.08838834764831843f;  // 1/sqrt(128)
  const float NEG = -30000.0f;

  const u32 tK = ctrl[0];
  const u64 KrK = (((u64)ctrl[2]) << 32) | ctrl[3];
  const u32 tV = ctrl[8];
  const u64 KrV = (((u64)ctrl[10]) << 32) | ctrl[11];

  const int cch = (tid & 15) * 8;   // staging channel base (both K and V)
  float ksc[8], vsc[8];
#pragma unroll
  for (int j = 0; j < 8; ++j) {
    ksc[j] = kscale[h * HD + cch + j];
    vsc[j] = vscale[h * HD + cch + j];
  }

  // Q A-frags (bf16): A[m=l16][k=quad*8+j], 4 k-steps of 32
  short8 qf[4];
  {
    const float* qp = Q + ((size_t)(h * SEQ + qb + w * 16 + l16)) * HD + quad * 8;
#pragma unroll
    for (int c = 0; c < 4; ++c) {
      f32x4 a = *(const f32x4*)(qp + c * 32);
      f32x4 b = *(const f32x4*)(qp + c * 32 + 4);
#pragma unroll
      for (int j = 0; j < 4; ++j) {
        qf[c][j] = (short)f2bf(a[j]);
        qf[c][4 + j] = (short)f2bf(b[j]);
      }
    }
  }

  f32x4 o[8];
#pragma unroll
  for (int i = 0; i < 8; ++i) o[i] = (f32x4){0.f, 0.f, 0.f, 0.f};
  float mrow[4], lrow[4];
#pragma unroll
  for (int r = 0; r < 4; ++r) { mrow[r] = NEG; lrow[r] = 0.f; }

  const int ktiles = qt + 1;
  for (int kt = 0; kt < ktiles; ++kt) {
    const int kb = kt << 6;
    __syncthreads();
    // stage K tile with fp32 dequant -> bf16
    {
      const int r0 = tid >> 4;
      const float* kp = K + (size_t)(h * SEQ + kb) * HD;
#pragma unroll
      for (int i = 0; i < 4; ++i) {
        const int row = r0 + i * 16;
        f32x4 x0 = *(const f32x4*)(kp + (size_t)row * HD + cch);
        f32x4 x1 = *(const f32x4*)(kp + (size_t)row * HD + cch + 4);
        const u32 bidx = ((u32)(h * SEQ + kb + row) << 7) + (u32)cch;
        short8 yv;
#pragma unroll
        for (int j = 0; j < 4; ++j) {
          yv[j]     = (short)f2bf(dqf(x0[j], tK, KrK, bidx + j,     false, ksc[j]));
          yv[4 + j] = (short)f2bf(dqf(x1[j], tK, KrK, bidx + 4 + j, false, ksc[4 + j]));
        }
        *(short8*)(&ks[row][cch]) = yv;
      }
    }
    // stage V transposed with fp32 dequant (+sink passthrough) -> bf16
    {
      const float* vp = V + (size_t)(h * SEQ + kb) * HD;
#pragma unroll
      for (int i = 0; i < 4; ++i) {
        const int tchunk = tid + i * 256;           // 0..1023
        const int s = tchunk >> 4;                  // 0..63 (tchunk&15 == tid&15)
        const int tok = kb + s;
        const bool sink = tok < 4;
        f32x4 x0 = *(const f32x4*)(vp + (size_t)s * HD + cch);
        f32x4 x1 = *(const f32x4*)(vp + (size_t)s * HD + cch + 4);
        const u32 bidx = ((u32)(h * SEQ + tok) << 7) + (u32)cch;
#pragma unroll
        for (int j = 0; j < 4; ++j) {
          vt[cch + j][s]     = f2bf(dqf(x0[j], tV, KrV, bidx + j,     sink, vsc[j]));
          vt[cch + 4 + j][s] = f2bf(dqf(x1[j], tV, KrV, bidx + 4 + j, sink, vsc[4 + j]));
        }
      }
    }
    __syncthreads();

    // S = Q K^T
    f32x4 sa[4];
#pragma unroll
    for (int ni = 0; ni < 4; ++ni) {
      f32x4 acc = (f32x4){0.f, 0.f, 0.f, 0.f};
#pragma unroll
      for (int c = 0; c < 4; ++c) {
        short8 kf = *(const short8*)(&ks[ni * 16 + l16][c * 32 + quad * 8]);
        acc = __builtin_amdgcn_mfma_f32_16x16x32_bf16(qf[c], kf, acc, 0, 0, 0);
      }
      sa[ni] = acc;
    }
    const bool diag = (kb == qb);
#pragma unroll
    for (int ni = 0; ni < 4; ++ni)
#pragma unroll
      for (int r = 0; r < 4; ++r) {
        float sv = sa[ni][r] * SM_SCALE;
        if (diag) {
          const int qr = w * 16 + quad * 4 + r;
          const int kc = ni * 16 + l16;
          if (kc > qr) sv = NEG;
        }
        sa[ni][r] = sv;
      }
    // online softmax (C-layout row = quad*4+r, replicated over 16 l16 lanes)
    float alpha[4];
#pragma unroll
    for (int r = 0; r < 4; ++r) {
      float mx = fmaxf(fmaxf(sa[0][r], sa[1][r]), fmaxf(sa[2][r], sa[3][r]));
      mx = fmaxf(mx, __shfl_xor(mx, 1));
      mx = fmaxf(mx, __shfl_xor(mx, 2));
      mx = fmaxf(mx, __shfl_xor(mx, 4));
      mx = fmaxf(mx, __shfl_xor(mx, 8));
      const float mn = fmaxf(mrow[r], mx);
      alpha[r] = __expf(mrow[r] - mn);
      mrow[r] = mn;
      float sum = 0.f;
#pragma unroll
      for (int ni = 0; ni < 4; ++ni) {
        const float p = __expf(sa[ni][r] - mn);
        sa[ni][r] = p;
        sum += p;
      }
      sum += __shfl_xor(sum, 1);
      sum += __shfl_xor(sum, 2);
      sum += __shfl_xor(sum, 4);
      sum += __shfl_xor(sum, 8);
      lrow[r] = lrow[r] * alpha[r] + sum;
    }
    // P (C-layout) -> LDS (A-layout transform via roundtrip)
#pragma unroll
    for (int ni = 0; ni < 4; ++ni)
#pragma unroll
      for (int r = 0; r < 4; ++r)
        pl[w][quad * 4 + r][ni * 16 + l16] = f2bf(sa[ni][r]);
    __syncthreads();
    // rescale O
#pragma unroll
    for (int i = 0; i < 8; ++i)
#pragma unroll
      for (int r = 0; r < 4; ++r) o[i][r] *= alpha[r];
    // O += P V
#pragma unroll
    for (int kc = 0; kc < 2; ++kc) {
      short8 af = *(const short8*)(&pl[w][l16][kc * 32 + quad * 8]);
#pragma unroll
      for (int ds = 0; ds < 8; ++ds) {
        short8 vf = *(const short8*)(&vt[ds * 16 + l16][kc * 32 + quad * 8]);
        o[ds] = __builtin_amdgcn_mfma_f32_16x16x32_bf16(af, vf, o[ds], 0, 0, 0);
      }
    }
  }
  // epilogue: fp32 store
#pragma unroll
  for (int r = 0; r < 4; ++r) {
    const float inv = 1.0f / lrow[r];
    const int qr = qb + w * 16 + quad * 4 + r;
    float* op = Out + ((size_t)(h * SEQ + qr)) * HD + l16;
#pragma unroll
    for (int ds = 0; ds < 8; ++ds) op[ds * 16] = o[ds][r] * inv;
  }
}

// ---------------- launcher ----------------
extern "C" void kernel_launch(void* const* d_in, const int* in_sizes, int n_in,
                              void* d_out, int out_size, void* d_ws, size_t ws_size,
                              hipStream_t stream) {
  const float* q = (const float*)d_in[0];
  const float* k = (const float*)d_in[1];
  const float* v = (const float*)d_in[2];
  float* out = (float*)d_out;
  char* ws = (char*)d_ws;

  // workspace layout (~450 KB total)
  u32* ctrl    = (u32*)ws;                               // 256 B [K:0..7, V:8..15]
  u32* histK   = (u32*)(ws + 256);                       // 128 KB
  u32* histV   = (u32*)(ws + 256 + 131072);              // 128 KB
  u32* kmax    = (u32*)(ws + 256 + 262144);              // 16 KB
  u32* vmax    = (u32*)(ws + 256 + 262144 + 16384);      // 16 KB
  const size_t ZERO_BYTES = 256 + 262144 + 32768;        // 295168
  float* kscale = (float*)(ws + ZERO_BYTES);             // 16 KB
  float* vscale = (float*)(ws + ZERO_BYTES + 16384);     // 16 KB
  u32* caK = (u32*)(ws + ZERO_BYTES + 32768);            // 32 KB
  u32* ciK = caK + CAND_CAP;                             // 32 KB
  u32* caV = ciK + CAND_CAP;                             // 32 KB
  u32* ciV = caV + CAND_CAP;                             // 32 KB

  hipMemsetAsync(ws, 0, ZERO_BYTES, stream);
  hist_kernel<<<128, 256, 0, stream>>>(k, v, histK, histV);
  thresh_kernel<<<2, 256, 0, stream>>>(histK, histV, ctrl);
  cand_kernel<<<dim3(256, 2), 256, 0, stream>>>(k, v, ctrl, caK, ciK, caV, ciV);
  ksel_kernel<<<2, 256, 0, stream>>>(ctrl, caK, ciK, caV, ciV);
  maxabs_kernel<<<dim3(32, 16, 2), 128, 0, stream>>>(k, v, ctrl, kmax, vmax);
  scale_kernel<<<16, 256, 0, stream>>>(kmax, vmax, kscale, vscale);
  flash_kernel<<<32 * 32, 256, 0, stream>>>(q, k, v, ctrl, kscale, vscale, out);
}

// Round 4
// 457.881 us; speedup vs baseline: 2.8510x; 2.8510x over previous
//
#include <hip/hip_runtime.h>

typedef unsigned short u16;
typedef unsigned int u32;
typedef unsigned long long u64;
typedef __attribute__((ext_vector_type(8))) short short8;
typedef __attribute__((ext_vector_type(4))) float f32x4;

#define N_ELEM 8388608
#define NH 32
#define SEQ 2048
#define HD 128
#define KTOP 32768u
#define CAND_CAP 8192u

__device__ __forceinline__ u16 f2bf(float f) {
  union { float f; u32 u; } v; v.f = f;
  u32 r = v.u + 0x7fffu + ((v.u >> 16) & 1u);
  return (u16)(r >> 16);
}

// fp32 quant-dequant, exact reference semantics; keeps outliers & sinks verbatim
__device__ __forceinline__ float dqf(float x, u32 t, u64 Kr, u32 idx, bool sink, float scale) {
  union { float f; u32 u; } w; w.f = x;
  const u32 ab = w.u & 0x7fffffffu;
  const u32 bin = ab >> 16;
  const bool keep = sink || (bin > t) ||
                    (bin == t && ((((u64)ab) << 32) | (u32)(~idx)) >= Kr);
  if (keep) return x;
  float q = rintf(x / scale);            // round-half-even == jnp.round
  q = fminf(fmaxf(q, -8.0f), 7.0f);
  return q * scale;
}

// ---------------- K1: 32768-bin histogram of fp32 abs-bits>>16 ----------------
// 256 blocks x 256 thr; [0,128)->K, [128,256)->V. 64KB LDS packed u16 bins.
__global__ __launch_bounds__(256) void hist_kernel(const float* __restrict__ k,
                                                   const float* __restrict__ v,
                                                   u32* __restrict__ histK,
                                                   u32* __restrict__ histV) {
  __shared__ u32 sh[16384];
  const int tensor = blockIdx.x >> 7;
  const int bid = blockIdx.x & 127;
  const float* src = tensor ? v : k;
  u32* gh = tensor ? histV : histK;
  for (int i = threadIdx.x; i < 16384; i += 256) sh[i] = 0;
  __syncthreads();
  const int per = N_ELEM / 128;  // 65536
  const int base = bid * per;
  for (int i = threadIdx.x; i < per / 4; i += 256) {
    f32x4 x = *(const f32x4*)(src + base + i * 4);
#pragma unroll
    for (int j = 0; j < 4; ++j) {
      union { float f; u32 u; } w; w.f = x[j];
      u32 b = (w.u & 0x7fffffffu) >> 16;
      atomicAdd(&sh[b >> 1], 1u << ((b & 1u) * 16));
    }
  }
  __syncthreads();
  for (int i = threadIdx.x; i < 16384; i += 256) {
    u32 w = sh[i];
    u32 lo = w & 0xffffu, hi = w >> 16;
    if (lo) atomicAdd(&gh[2 * i], lo);
    if (hi) atomicAdd(&gh[2 * i + 1], hi);
  }
}

// ---------------- K2: threshold bin t + tie budget r ----------------
// ctrl per tensor (8 u32): [t, r, KrHi, KrLo, candCount, -, -, -]
__global__ __launch_bounds__(256) void thresh_kernel(const u32* __restrict__ histK,
                                                     const u32* __restrict__ histV,
                                                     u32* __restrict__ ctrl) {
  const u32* hist = blockIdx.x ? histV : histK;
  u32* c = ctrl + blockIdx.x * 8;
  __shared__ u32 part[256];
  u32 s = 0;
  for (int i = 0; i < 128; ++i) s += hist[threadIdx.x * 128 + i];
  part[threadIdx.x] = s;
  __syncthreads();
  if (threadIdx.x == 0) {
    u32 cum = 0;
    int chunk = 255;
    while (chunk > 0 && cum + part[chunk] < KTOP) { cum += part[chunk]; --chunk; }
    int b = chunk * 128 + 127;
    while (b > 0 && cum + hist[b] < KTOP) { cum += hist[b]; --b; }
    c[0] = (u32)b;
    c[1] = KTOP - cum;
  }
}

// ---------------- K3: fused candidate gather + per-(h,d) max over bin<t -------------
// grid (128, 2): block handles head h = bx>>2, row-quarter q = bx&3 (512 rows).
// Candidates (bin==t) appended globally; column max over strictly-below-threshold
// elements (sinks excluded for V); bin==t non-outliers fixed up later by maxfix.
__global__ __launch_bounds__(256) void candmax_kernel(const float* __restrict__ k,
                                                      const float* __restrict__ v,
                                                      u32* __restrict__ ctrl,
                                                      u32* __restrict__ caK, u32* __restrict__ ciK,
                                                      u32* __restrict__ caV, u32* __restrict__ ciV,
                                                      u32* __restrict__ kmax,
                                                      u32* __restrict__ vmax) {
  __shared__ u32 colmax[128];
  const int tensor = blockIdx.y;
  const float* src = tensor ? v : k;
  u32* ca = tensor ? caV : caK;
  u32* ci = tensor ? ciV : ciK;
  u32* cnt = &ctrl[tensor * 8 + 4];
  u32* mbuf = tensor ? vmax : kmax;
  const u32 t = ctrl[tensor * 8 + 0];
  const int h = blockIdx.x >> 2;
  const int q = blockIdx.x & 3;
  const int tid = threadIdx.x;
  if (tid < 128) colmax[tid] = 0;
  __syncthreads();
  const int c0 = 4 * (tid & 31);
  u32 mx[4] = {0, 0, 0, 0};
  for (int p = 0; p < 64; ++p) {
    const int s = q * 512 + p * 8 + (tid >> 5);
    const u32 idx = ((u32)(h * SEQ + s) << 7) + (u32)c0;
    f32x4 x = *(const f32x4*)(src + idx);
    const bool skipmax = (tensor == 1 && s < 4);
#pragma unroll
    for (int j = 0; j < 4; ++j) {
      union { float f; u32 u; } w; w.f = x[j];
      const u32 ab = w.u & 0x7fffffffu;
      const u32 bin = ab >> 16;
      if (bin == t) {
        u32 slot = atomicAdd(cnt, 1u);
        if (slot < CAND_CAP) { ca[slot] = ab; ci[slot] = idx + j; }
      }
      if (bin < t && !skipmax && ab > mx[j]) mx[j] = ab;
    }
  }
#pragma unroll
  for (int j = 0; j < 4; ++j) atomicMax(&colmax[c0 + j], mx[j]);
  __syncthreads();
  if (tid < 128) atomicMax(&mbuf[h * HD + tid], colmax[tid]);
}

// ---------------- K4: Kr = r-th largest key among candidates (LDS-cached) -----------
// key = (abs_bits<<32) | ~idx. grid (32, 2); each block caches all keys in LDS.
__global__ __launch_bounds__(256) void ksel_kernel(u32* __restrict__ ctrl,
                                                   const u32* __restrict__ caK, const u32* __restrict__ ciK,
                                                   const u32* __restrict__ caV, const u32* __restrict__ ciV) {
  __shared__ u64 keys[CAND_CAP];
  const int tensor = blockIdx.y;
  u32* c = ctrl + tensor * 8;
  const u32 r = c[1];
  u32 T = c[4];
  if (T > CAND_CAP) T = CAND_CAP;
  const u32* ca = tensor ? caV : caK;
  const u32* ci = tensor ? ciV : ciK;
  for (u32 j = threadIdx.x; j < T; j += 256)
    keys[j] = (((u64)ca[j]) << 32) | (u32)(~ci[j]);
  __syncthreads();
  for (u32 i = blockIdx.x * 256 + threadIdx.x; i < T; i += 32 * 256) {
    const u64 ki = keys[i];
    u32 cnt = 0;
    for (u32 j = 0; j < T; ++j) cnt += (keys[j] > ki) ? 1u : 0u;
    if (cnt == r - 1) { c[2] = (u32)(ki >> 32); c[3] = (u32)ki; }
  }
}

// ---------------- K5: fold bin==t non-outliers into the column max ----------------
__global__ __launch_bounds__(256) void maxfix_kernel(const u32* __restrict__ ctrl,
                                                     const u32* __restrict__ caK, const u32* __restrict__ ciK,
                                                     const u32* __restrict__ caV, const u32* __restrict__ ciV,
                                                     u32* __restrict__ kmax,
                                                     u32* __restrict__ vmax) {
  const int tensor = blockIdx.x;
  const u32* c = ctrl + tensor * 8;
  const u64 Kr = (((u64)c[2]) << 32) | c[3];
  u32 T = c[4];
  if (T > CAND_CAP) T = CAND_CAP;
  const u32* ca = tensor ? caV : caK;
  const u32* ci = tensor ? ciV : ciK;
  u32* mbuf = tensor ? vmax : kmax;
  for (u32 i = threadIdx.x; i < T; i += 256) {
    const u32 ab = ca[i], idx = ci[i];
    const u64 key = (((u64)ab) << 32) | (u32)(~idx);
    if (key >= Kr) continue;                         // outlier -> excluded
    if (tensor == 1 && ((idx >> 7) & 2047) < 4) continue;  // V sink -> excluded
    const u32 h = idx >> 18, d = idx & 127;
    atomicMax(&mbuf[h * HD + d], ab);
  }
}

// ---------------- K6: scales: max(|.|,eps)/7 ----------------
__global__ __launch_bounds__(256) void scale_kernel(const u32* __restrict__ kmax,
                                                    const u32* __restrict__ vmax,
                                                    float* __restrict__ kscale,
                                                    float* __restrict__ vscale) {
  const int i = blockIdx.x * 256 + threadIdx.x;
  if (i < NH * HD) {
    union { u32 u; float f; } a, b;
    a.u = kmax[i]; b.u = vmax[i];
    kscale[i] = fmaxf(a.f, 1e-6f) / 7.0f;
    vscale[i] = fmaxf(b.f, 1e-6f) / 7.0f;
  }
}

// ---------------- K7: reconstruct K -> bf16 krec (row-major), elementwise -----------
__global__ __launch_bounds__(256) void recon_k_kernel(const float* __restrict__ K,
                                                      const u32* __restrict__ ctrl,
                                                      const float* __restrict__ kscale,
                                                      u16* __restrict__ krec) {
  const u32 t = ctrl[0];
  const u64 Kr = (((u64)ctrl[2]) << 32) | ctrl[3];
  const int stride = gridDim.x * 256;
  for (int i = blockIdx.x * 256 + threadIdx.x; i < N_ELEM / 4; i += stride) {
    const u32 e = (u32)i * 4;
    const u32 d0 = e & 127, h = e >> 18;
    f32x4 x = *(const f32x4*)(K + e);
    f32x4 sc = *(const f32x4*)(kscale + h * HD + d0);
    u16 y[4];
#pragma unroll
    for (int j = 0; j < 4; ++j) y[j] = f2bf(dqf(x[j], t, Kr, e + j, false, sc[j]));
    *(u32*)(krec + e) = ((u32)y[0]) | (((u32)y[1]) << 16);
    *(u32*)(krec + e + 2) = ((u32)y[2]) | (((u32)y[3]) << 16);
  }
}

// ---------------- K8: reconstruct V -> bf16 vrecT, 64-token-tile transposed ---------
// Output layout: tile (h, sb) of 128ch x 64tok contiguous 16KB at (h*32+sb)*8192.
__global__ __launch_bounds__(256) void recon_vt_kernel(const float* __restrict__ V,
                                                       const u32* __restrict__ ctrl,
                                                       const float* __restrict__ vscale,
                                                       u16* __restrict__ vrecT) {
  __shared__ u32 ld[64][68];   // [d-pair][s_local], 2 bf16 packed per u32
  const u32 t = ctrl[8];
  const u64 Kr = (((u64)ctrl[10]) << 32) | ctrl[11];
  const int h = blockIdx.x, sb = blockIdx.y;
  const int tid = threadIdx.x;
  const int d0 = 4 * (tid & 31);
  f32x4 sc = *(const f32x4*)(vscale + h * HD + d0);
#pragma unroll
  for (int p = 0; p < 8; ++p) {
    const int sl = p * 8 + (tid >> 5);
    const int tok = sb * 64 + sl;
    const bool sink = tok < 4;
    const u32 idx = ((u32)(h * SEQ + tok) << 7) + (u32)d0;
    f32x4 x = *(const f32x4*)(V + idx);
    u16 y[4];
#pragma unroll
    for (int j = 0; j < 4; ++j) y[j] = f2bf(dqf(x[j], t, Kr, idx + j, sink, sc[j]));
    ld[(d0 >> 1)][sl] = ((u32)y[0]) | (((u32)y[1]) << 16);
    ld[(d0 >> 1) + 1][sl] = ((u32)y[2]) | (((u32)y[3]) << 16);
  }
  __syncthreads();
  // write out: thread -> row d = tid>>1, s-half = (tid&1)*32
  const int d = tid >> 1, so = (tid & 1) * 32, e = d & 1;
  u16* outp = vrecT + (size_t)(h * 32 + sb) * 8192 + d * 64 + so;
#pragma unroll
  for (int i = 0; i < 4; ++i) {
    short8 y;
#pragma unroll
    for (int m = 0; m < 8; ++m) {
      const u32 w = ld[d >> 1][so + i * 8 + m];
      y[m] = (short)(u16)(w >> (16 * e));
    }
    *(short8*)(outp + i * 8) = y;
  }
}

// ---------------- K9: flash attention from precomputed bf16 krec/vrecT --------------
__global__ __launch_bounds__(256, 2) void flash_pre(const float* __restrict__ Q,
                                                    const u16* __restrict__ krec,
                                                    const u16* __restrict__ vrecT,
                                                    float* __restrict__ Out) {
  __shared__ u16 ks[64][136];     // K tile (token x channel), pad 128->136
  __shared__ u16 vt[128][72];     // V^T tile (channel x token), pad 64->72
  __shared__ u16 pl[4][16][72];   // per-wave P tile

  const int blk = blockIdx.x;
  const int h = blk >> 5;
  const int qt = 31 - (blk & 31);
  const int qb = qt << 6;
  const int tid = threadIdx.x;
  const int w = tid >> 6, lane = tid & 63;
  const int l16 = lane & 15, quad = lane >> 4;
  const float SM_SCALE = 0.08838834764831843f;
  const float NEG = -30000.0f;

  // Q A-frags (fp32 -> bf16)
  short8 qf[4];
  {
    const float* qp = Q + ((size_t)(h * SEQ + qb + w * 16 + l16)) * HD + quad * 8;
#pragma unroll
    for (int c = 0; c < 4; ++c) {
      f32x4 a = *(const f32x4*)(qp + c * 32);
      f32x4 b = *(const f32x4*)(qp + c * 32 + 4);
#pragma unroll
      for (int j = 0; j < 4; ++j) {
        qf[c][j] = (short)f2bf(a[j]);
        qf[c][4 + j] = (short)f2bf(b[j]);
      }
    }
  }

  f32x4 o[8];
#pragma unroll
  for (int i = 0; i < 8; ++i) o[i] = (f32x4){0.f, 0.f, 0.f, 0.f};
  float mrow[4], lrow[4];
#pragma unroll
  for (int r = 0; r < 4; ++r) { mrow[r] = NEG; lrow[r] = 0.f; }

  const int ktiles = qt + 1;
  for (int kt = 0; kt < ktiles; ++kt) {
    const int kb = kt << 6;
    __syncthreads();
    // stage K tile: 64 rows x 256B, pure bf16 vector copy
    {
      const int row = tid >> 2;
      const int qo = (tid & 3) * 32;
      const u16* kp = krec + ((size_t)(h * SEQ + kb + row)) * HD + qo;
#pragma unroll
      for (int i = 0; i < 4; ++i)
        *(short8*)(&ks[row][qo + i * 8]) = *(const short8*)(kp + i * 8);
    }
    // stage V^T tile from blocked pre-transposed vrecT: 128 rows x 128B
    {
      const int d = tid >> 1;
      const int so = (tid & 1) * 32;
      const u16* vp = vrecT + (size_t)(h * 32 + kt) * 8192 + d * 64 + so;
#pragma unroll
      for (int i = 0; i < 4; ++i)
        *(short8*)(&vt[d][so + i * 8]) = *(const short8*)(vp + i * 8);
    }
    __syncthreads();

    // S = Q K^T
    f32x4 sa[4];
#pragma unroll
    for (int ni = 0; ni < 4; ++ni) {
      f32x4 acc = (f32x4){0.f, 0.f, 0.f, 0.f};
#pragma unroll
      for (int c = 0; c < 4; ++c) {
        short8 kf = *(const short8*)(&ks[ni * 16 + l16][c * 32 + quad * 8]);
        acc = __builtin_amdgcn_mfma_f32_16x16x32_bf16(qf[c], kf, acc, 0, 0, 0);
      }
      sa[ni] = acc;
    }
    const bool diag = (kb == qb);
#pragma unroll
    for (int ni = 0; ni < 4; ++ni)
#pragma unroll
      for (int r = 0; r < 4; ++r) {
        float sv = sa[ni][r] * SM_SCALE;
        if (diag) {
          const int qr = w * 16 + quad * 4 + r;
          const int kc = ni * 16 + l16;
          if (kc > qr) sv = NEG;
        }
        sa[ni][r] = sv;
      }
    // online softmax
    float alpha[4];
#pragma unroll
    for (int r = 0; r < 4; ++r) {
      float mx = fmaxf(fmaxf(sa[0][r], sa[1][r]), fmaxf(sa[2][r], sa[3][r]));
      mx = fmaxf(mx, __shfl_xor(mx, 1));
      mx = fmaxf(mx, __shfl_xor(mx, 2));
      mx = fmaxf(mx, __shfl_xor(mx, 4));
      mx = fmaxf(mx, __shfl_xor(mx, 8));
      const float mn = fmaxf(mrow[r], mx);
      alpha[r] = __expf(mrow[r] - mn);
      mrow[r] = mn;
      float sum = 0.f;
#pragma unroll
      for (int ni = 0; ni < 4; ++ni) {
        const float p = __expf(sa[ni][r] - mn);
        sa[ni][r] = p;
        sum += p;
      }
      sum += __shfl_xor(sum, 1);
      sum += __shfl_xor(sum, 2);
      sum += __shfl_xor(sum, 4);
      sum += __shfl_xor(sum, 8);
      lrow[r] = lrow[r] * alpha[r] + sum;
    }
    // P -> LDS (C->A layout roundtrip)
#pragma unroll
    for (int ni = 0; ni < 4; ++ni)
#pragma unroll
      for (int r = 0; r < 4; ++r)
        pl[w][quad * 4 + r][ni * 16 + l16] = f2bf(sa[ni][r]);
    __syncthreads();
#pragma unroll
    for (int i = 0; i < 8; ++i)
#pragma unroll
      for (int r = 0; r < 4; ++r) o[i][r] *= alpha[r];
    // O += P V
#pragma unroll
    for (int kc = 0; kc < 2; ++kc) {
      short8 af = *(const short8*)(&pl[w][l16][kc * 32 + quad * 8]);
#pragma unroll
      for (int ds = 0; ds < 8; ++ds) {
        short8 vf = *(const short8*)(&vt[ds * 16 + l16][kc * 32 + quad * 8]);
        o[ds] = __builtin_amdgcn_mfma_f32_16x16x32_bf16(af, vf, o[ds], 0, 0, 0);
      }
    }
  }
#pragma unroll
  for (int r = 0; r < 4; ++r) {
    const float inv = 1.0f / lrow[r];
    const int qr = qb + w * 16 + quad * 4 + r;
    float* op = Out + ((size_t)(h * SEQ + qr)) * HD + l16;
#pragma unroll
    for (int ds = 0; ds < 8; ++ds) op[ds * 16] = o[ds][r] * inv;
  }
}

// ---------------- fallback flash (round-3 passing version, inline dequant) ----------
__global__ __launch_bounds__(256, 2) void flash_fb(const float* __restrict__ Q,
                                                   const float* __restrict__ K,
                                                   const float* __restrict__ V,
                                                   const u32* __restrict__ ctrl,
                                                   const float* __restrict__ kscale,
                                                   const float* __restrict__ vscale,
                                                   float* __restrict__ Out) {
  __shared__ u16 ks[64][136];
  __shared__ u16 vt[128][72];
  __shared__ u16 pl[4][16][72];
  const int blk = blockIdx.x;
  const int h = blk >> 5;
  const int qt = 31 - (blk & 31);
  const int qb = qt << 6;
  const int tid = threadIdx.x;
  const int w = tid >> 6, lane = tid & 63;
  const int l16 = lane & 15, quad = lane >> 4;
  const float SM_SCALE = 0.08838834764831843f;
  const float NEG = -30000.0f;
  const u32 tK = ctrl[0];
  const u64 KrK = (((u64)ctrl[2]) << 32) | ctrl[3];
  const u32 tV = ctrl[8];
  const u64 KrV = (((u64)ctrl[10]) << 32) | ctrl[11];
  const int cch = (tid & 15) * 8;
  float ksc[8], vsc[8];
#pragma unroll
  for (int j = 0; j < 8; ++j) {
    ksc[j] = kscale[h * HD + cch + j];
    vsc[j] = vscale[h * HD + cch + j];
  }
  short8 qf[4];
  {
    const float* qp = Q + ((size_t)(h * SEQ + qb + w * 16 + l16)) * HD + quad * 8;
#pragma unroll
    for (int c = 0; c < 4; ++c) {
      f32x4 a = *(const f32x4*)(qp + c * 32);
      f32x4 b = *(const f32x4*)(qp + c * 32 + 4);
#pragma unroll
      for (int j = 0; j < 4; ++j) {
        qf[c][j] = (short)f2bf(a[j]);
        qf[c][4 + j] = (short)f2bf(b[j]);
      }
    }
  }
  f32x4 o[8];
#pragma unroll
  for (int i = 0; i < 8; ++i) o[i] = (f32x4){0.f, 0.f, 0.f, 0.f};
  float mrow[4], lrow[4];
#pragma unroll
  for (int r = 0; r < 4; ++r) { mrow[r] = NEG; lrow[r] = 0.f; }
  const int ktiles = qt + 1;
  for (int kt = 0; kt < ktiles; ++kt) {
    const int kb = kt << 6;
    __syncthreads();
    {
      const int r0 = tid >> 4;
      const float* kp = K + (size_t)(h * SEQ + kb) * HD;
#pragma unroll
      for (int i = 0; i < 4; ++i) {
        const int row = r0 + i * 16;
        f32x4 x0 = *(const f32x4*)(kp + (size_t)row * HD + cch);
        f32x4 x1 = *(const f32x4*)(kp + (size_t)row * HD + cch + 4);
        const u32 bidx = ((u32)(h * SEQ + kb + row) << 7) + (u32)cch;
        short8 yv;
#pragma unroll
        for (int j = 0; j < 4; ++j) {
          yv[j]     = (short)f2bf(dqf(x0[j], tK, KrK, bidx + j,     false, ksc[j]));
          yv[4 + j] = (short)f2bf(dqf(x1[j], tK, KrK, bidx + 4 + j, false, ksc[4 + j]));
        }
        *(short8*)(&ks[row][cch]) = yv;
      }
    }
    {
      const float* vp = V + (size_t)(h * SEQ + kb) * HD;
#pragma unroll
      for (int i = 0; i < 4; ++i) {
        const int tchunk = tid + i * 256;
        const int s = tchunk >> 4;
        const int tok = kb + s;
        const bool sink = tok < 4;
        f32x4 x0 = *(const f32x4*)(vp + (size_t)s * HD + cch);
        f32x4 x1 = *(const f32x4*)(vp + (size_t)s * HD + cch + 4);
        const u32 bidx = ((u32)(h * SEQ + tok) << 7) + (u32)cch;
#pragma unroll
        for (int j = 0; j < 4; ++j) {
          vt[cch + j][s]     = f2bf(dqf(x0[j], tV, KrV, bidx + j,     sink, vsc[j]));
          vt[cch + 4 + j][s] = f2bf(dqf(x1[j], tV, KrV, bidx + 4 + j, sink, vsc[4 + j]));
        }
      }
    }
    __syncthreads();
    f32x4 sa[4];
#pragma unroll
    for (int ni = 0; ni < 4; ++ni) {
      f32x4 acc = (f32x4){0.f, 0.f, 0.f, 0.f};
#pragma unroll
      for (int c = 0; c < 4; ++c) {
        short8 kf = *(const short8*)(&ks[ni * 16 + l16][c * 32 + quad * 8]);
        acc = __builtin_amdgcn_mfma_f32_16x16x32_bf16(qf[c], kf, acc, 0, 0, 0);
      }
      sa[ni] = acc;
    }
    const bool diag = (kb == qb);
#pragma unroll
    for (int ni = 0; ni < 4; ++ni)
#pragma unroll
      for (int r = 0; r < 4; ++r) {
        float sv = sa[ni][r] * SM_SCALE;
        if (diag) {
          const int qr = w * 16 + quad * 4 + r;
          const int kc = ni * 16 + l16;
          if (kc > qr) sv = NEG;
        }
        sa[ni][r] = sv;
      }
    float alpha[4];
#pragma unroll
    for (int r = 0; r < 4; ++r) {
      float mx = fmaxf(fmaxf(sa[0][r], sa[1][r]), fmaxf(sa[2][r], sa[3][r]));
      mx = fmaxf(mx, __shfl_xor(mx, 1));
      mx = fmaxf(mx, __shfl_xor(mx, 2));
      mx = fmaxf(mx, __shfl_xor(mx, 4));
      mx = fmaxf(mx, __shfl_xor(mx, 8));
      const float mn = fmaxf(mrow[r], mx);
      alpha[r] = __expf(mrow[r] - mn);
      mrow[r] = mn;
      float sum = 0.f;
#pragma unroll
      for (int ni = 0; ni < 4; ++ni) {
        const float p = __expf(sa[ni][r] - mn);
        sa[ni][r] = p;
        sum += p;
      }
      sum += __shfl_xor(sum, 1);
      sum += __shfl_xor(sum, 2);
      sum += __shfl_xor(sum, 4);
      sum += __shfl_xor(sum, 8);
      lrow[r] = lrow[r] * alpha[r] + sum;
    }
#pragma unroll
    for (int ni = 0; ni < 4; ++ni)
#pragma unroll
      for (int r = 0; r < 4; ++r)
        pl[w][quad * 4 + r][ni * 16 + l16] = f2bf(sa[ni][r]);
    __syncthreads();
#pragma unroll
    for (int i = 0; i < 8; ++i)
#pragma unroll
      for (int r = 0; r < 4; ++r) o[i][r] *= alpha[r];
#pragma unroll
    for (int kc = 0; kc < 2; ++kc) {
      short8 af = *(const short8*)(&pl[w][l16][kc * 32 + quad * 8]);
#pragma unroll
      for (int ds = 0; ds < 8; ++ds) {
        short8 vf = *(const short8*)(&vt[ds * 16 + l16][kc * 32 + quad * 8]);
        o[ds] = __builtin_amdgcn_mfma_f32_16x16x32_bf16(af, vf, o[ds], 0, 0, 0);
      }
    }
  }
#pragma unroll
  for (int r = 0; r < 4; ++r) {
    const float inv = 1.0f / lrow[r];
    const int qr = qb + w * 16 + quad * 4 + r;
    float* op = Out + ((size_t)(h * SEQ + qr)) * HD + l16;
#pragma unroll
    for (int ds = 0; ds < 8; ++ds) op[ds * 16] = o[ds][r] * inv;
  }
}

// ---------------- launcher ----------------
extern "C" void kernel_launch(void* const* d_in, const int* in_sizes, int n_in,
                              void* d_out, int out_size, void* d_ws, size_t ws_size,
                              hipStream_t stream) {
  const float* q = (const float*)d_in[0];
  const float* k = (const float*)d_in[1];
  const float* v = (const float*)d_in[2];
  float* out = (float*)d_out;
  char* ws = (char*)d_ws;

  // workspace layout
  u32* ctrl    = (u32*)ws;                               // 256 B
  u32* histK   = (u32*)(ws + 256);                       // 128 KB
  u32* histV   = (u32*)(ws + 256 + 131072);              // 128 KB
  u32* kmax    = (u32*)(ws + 262400);                    // 16 KB
  u32* vmax    = (u32*)(ws + 278784);                    // 16 KB
  const size_t ZERO_BYTES = 295168;                      // ctrl+hists+maxes
  float* kscale = (float*)(ws + 295168);                 // 16 KB
  float* vscale = (float*)(ws + 311552);                 // 16 KB
  u32* caK = (u32*)(ws + 327936);                        // 32 KB
  u32* ciK = caK + CAND_CAP;
  u32* caV = ciK + CAND_CAP;
  u32* ciV = caV + CAND_CAP;
  u16* krec  = (u16*)(ws + 458752);                      // 16 MB
  u16* vrecT = (u16*)(ws + 458752 + 16777216);           // 16 MB
  const size_t NEED = 458752 + 2ull * 16777216;          // 34013184

  hipMemsetAsync(ws, 0, ZERO_BYTES, stream);
  hist_kernel<<<256, 256, 0, stream>>>(k, v, histK, histV);
  thresh_kernel<<<2, 256, 0, stream>>>(histK, histV, ctrl);
  candmax_kernel<<<dim3(128, 2), 256, 0, stream>>>(k, v, ctrl, caK, ciK, caV, ciV, kmax, vmax);
  ksel_kernel<<<dim3(32, 2), 256, 0, stream>>>(ctrl, caK, ciK, caV, ciV);
  maxfix_kernel<<<2, 256, 0, stream>>>(ctrl, caK, ciK, caV, ciV, kmax, vmax);
  scale_kernel<<<16, 256, 0, stream>>>(kmax, vmax, kscale, vscale);
  if (ws_size >= NEED) {
    recon_k_kernel<<<2048, 256, 0, stream>>>(k, ctrl, kscale, krec);
    recon_vt_kernel<<<dim3(32, 32), 256, 0, stream>>>(v, ctrl, vscale, vrecT);
    flash_pre<<<32 * 32, 256, 0, stream>>>(q, krec, vrecT, out);
  } else {
    flash_fb<<<32 * 32, 256, 0, stream>>>(q, k, v, ctrl, kscale, vscale, out);
  }
}

// Round 5
// 360.455 us; speedup vs baseline: 3.6216x; 1.2703x over previous
//
#include <hip/hip_runtime.h>

typedef unsigned short u16;
typedef unsigned int u32;
typedef unsigned long long u64;
typedef __attribute__((ext_vector_type(8))) short short8;
typedef __attribute__((ext_vector_type(4))) float f32x4;

#define N_ELEM 8388608
#define NH 32
#define SEQ 2048
#define HD 128
#define KTOP 32768u
#define CAND_CAP 8192u

__device__ __forceinline__ u16 f2bf(float f) {
  union { float f; u32 u; } v; v.f = f;
  u32 r = v.u + 0x7fffu + ((v.u >> 16) & 1u);
  return (u16)(r >> 16);
}

// fp32 quant-dequant, exact reference semantics; keeps outliers & sinks verbatim
__device__ __forceinline__ float dqf(float x, u32 t, u64 Kr, u32 idx, bool sink, float scale) {
  union { float f; u32 u; } w; w.f = x;
  const u32 ab = w.u & 0x7fffffffu;
  const u32 bin = ab >> 16;
  const bool keep = sink || (bin > t) ||
                    (bin == t && ((((u64)ab) << 32) | (u32)(~idx)) >= Kr);
  if (keep) return x;
  float q = rintf(x / scale);            // round-half-even == jnp.round
  q = fminf(fmaxf(q, -8.0f), 7.0f);
  return q * scale;
}

// DPP cross-lane (16-lane row) reductions: quad xor1, xor2, half-mirror, mirror
template<int CTRL>
__device__ __forceinline__ float dppmov(float x) {
  union { float f; int i; } a, b;
  a.f = x;
  b.i = __builtin_amdgcn_mov_dpp(a.i, CTRL, 0xF, 0xF, true);
  return b.f;
}
__device__ __forceinline__ float rowmax16(float x) {
  x = fmaxf(x, dppmov<0xB1>(x));    // quad_perm [1,0,3,2]  (xor 1)
  x = fmaxf(x, dppmov<0x4E>(x));    // quad_perm [2,3,0,1]  (xor 2)
  x = fmaxf(x, dppmov<0x141>(x));   // row_half_mirror      (xor 7 within 8)
  x = fmaxf(x, dppmov<0x140>(x));   // row_mirror           (xor 15 within 16)
  return x;
}
__device__ __forceinline__ float rowsum16(float x) {
  x += dppmov<0xB1>(x);
  x += dppmov<0x4E>(x);
  x += dppmov<0x141>(x);
  x += dppmov<0x140>(x);
  return x;
}

// ---------------- K1: 32768-bin histogram of fp32 abs-bits>>16 ----------------
__global__ __launch_bounds__(256) void hist_kernel(const float* __restrict__ k,
                                                   const float* __restrict__ v,
                                                   u32* __restrict__ histK,
                                                   u32* __restrict__ histV) {
  __shared__ u32 sh[16384];
  const int tensor = blockIdx.x >> 7;
  const int bid = blockIdx.x & 127;
  const float* src = tensor ? v : k;
  u32* gh = tensor ? histV : histK;
  for (int i = threadIdx.x; i < 16384; i += 256) sh[i] = 0;
  __syncthreads();
  const int per = N_ELEM / 128;  // 65536
  const int base = bid * per;
  for (int i = threadIdx.x; i < per / 4; i += 256) {
    f32x4 x = *(const f32x4*)(src + base + i * 4);
#pragma unroll
    for (int j = 0; j < 4; ++j) {
      union { float f; u32 u; } w; w.f = x[j];
      u32 b = (w.u & 0x7fffffffu) >> 16;
      atomicAdd(&sh[b >> 1], 1u << ((b & 1u) * 16));
    }
  }
  __syncthreads();
  for (int i = threadIdx.x; i < 16384; i += 256) {
    u32 w = sh[i];
    u32 lo = w & 0xffffu, hi = w >> 16;
    if (lo) atomicAdd(&gh[2 * i], lo);
    if (hi) atomicAdd(&gh[2 * i + 1], hi);
  }
}

// ---------------- K2: threshold bin t + tie budget r (LDS-cached scans) -------------
__global__ __launch_bounds__(256) void thresh_kernel(const u32* __restrict__ histK,
                                                     const u32* __restrict__ histV,
                                                     u32* __restrict__ ctrl) {
  const u32* hist = blockIdx.x ? histV : histK;
  u32* c = ctrl + blockIdx.x * 8;
  __shared__ u32 part[256];
  __shared__ u32 bins[128];
  __shared__ u32 sh_chunk, sh_cum;
  u32 s = 0;
  for (int i = 0; i < 128; ++i) s += hist[threadIdx.x * 128 + i];
  part[threadIdx.x] = s;
  __syncthreads();
  if (threadIdx.x == 0) {
    u32 cum = 0;
    int chunk = 255;
    while (chunk > 0 && cum + part[chunk] < KTOP) { cum += part[chunk]; --chunk; }
    sh_chunk = (u32)chunk; sh_cum = cum;
  }
  __syncthreads();
  const u32 chunk = sh_chunk;
  if (threadIdx.x < 128) bins[threadIdx.x] = hist[chunk * 128 + threadIdx.x];
  __syncthreads();
  if (threadIdx.x == 0) {
    u32 cum = sh_cum;
    int b = 127;
    while (b > 0 && cum + bins[b] < KTOP) { cum += bins[b]; --b; }
    c[0] = chunk * 128 + (u32)b;
    c[1] = KTOP - cum;
  }
}

// ---------------- K3: fused candidate gather + per-(h,d) max over bin<t -------------
// grid (256, 2): head h = bx>>3, row-eighth = bx&7 (256 rows/block) -> 2 blocks/CU.
__global__ __launch_bounds__(256) void candmax_kernel(const float* __restrict__ k,
                                                      const float* __restrict__ v,
                                                      u32* __restrict__ ctrl,
                                                      u32* __restrict__ caK, u32* __restrict__ ciK,
                                                      u32* __restrict__ caV, u32* __restrict__ ciV,
                                                      u32* __restrict__ kmax,
                                                      u32* __restrict__ vmax) {
  __shared__ u32 colmax[128];
  const int tensor = blockIdx.y;
  const float* src = tensor ? v : k;
  u32* ca = tensor ? caV : caK;
  u32* ci = tensor ? ciV : ciK;
  u32* cnt = &ctrl[tensor * 8 + 4];
  u32* mbuf = tensor ? vmax : kmax;
  const u32 t = ctrl[tensor * 8 + 0];
  const int h = blockIdx.x >> 3;
  const int q8 = blockIdx.x & 7;
  const int tid = threadIdx.x;
  if (tid < 128) colmax[tid] = 0;
  __syncthreads();
  const int c0 = 4 * (tid & 31);
  u32 mx[4] = {0, 0, 0, 0};
  for (int p = 0; p < 32; ++p) {
    const int s = q8 * 256 + p * 8 + (tid >> 5);
    const u32 idx = ((u32)(h * SEQ + s) << 7) + (u32)c0;
    f32x4 x = *(const f32x4*)(src + idx);
    const bool skipmax = (tensor == 1 && s < 4);
#pragma unroll
    for (int j = 0; j < 4; ++j) {
      union { float f; u32 u; } w; w.f = x[j];
      const u32 ab = w.u & 0x7fffffffu;
      const u32 bin = ab >> 16;
      if (bin == t) {
        u32 slot = atomicAdd(cnt, 1u);
        if (slot < CAND_CAP) { ca[slot] = ab; ci[slot] = idx + j; }
      }
      if (bin < t && !skipmax && ab > mx[j]) mx[j] = ab;
    }
  }
#pragma unroll
  for (int j = 0; j < 4; ++j) atomicMax(&colmax[c0 + j], mx[j]);
  __syncthreads();
  if (tid < 128) atomicMax(&mbuf[h * HD + tid], colmax[tid]);
}

// ---------------- K4: Kr = r-th largest key among candidates (LDS-cached) -----------
__global__ __launch_bounds__(256) void ksel_kernel(u32* __restrict__ ctrl,
                                                   const u32* __restrict__ caK, const u32* __restrict__ ciK,
                                                   const u32* __restrict__ caV, const u32* __restrict__ ciV) {
  __shared__ u64 keys[CAND_CAP];
  const int tensor = blockIdx.y;
  u32* c = ctrl + tensor * 8;
  const u32 r = c[1];
  u32 T = c[4];
  if (T > CAND_CAP) T = CAND_CAP;
  const u32* ca = tensor ? caV : caK;
  const u32* ci = tensor ? ciV : ciK;
  for (u32 j = threadIdx.x; j < T; j += 256)
    keys[j] = (((u64)ca[j]) << 32) | (u32)(~ci[j]);
  __syncthreads();
  for (u32 i = blockIdx.x * 256 + threadIdx.x; i < T; i += 32 * 256) {
    const u64 ki = keys[i];
    u32 cnt = 0;
    for (u32 j = 0; j < T; ++j) cnt += (keys[j] > ki) ? 1u : 0u;
    if (cnt == r - 1) { c[2] = (u32)(ki >> 32); c[3] = (u32)ki; }
  }
}

// ---------------- K5: maxfix (fold bin==t non-outliers) + scale, fused --------------
__global__ __launch_bounds__(256) void maxfix_scale_kernel(const u32* __restrict__ ctrl,
                                                           const u32* __restrict__ caK, const u32* __restrict__ ciK,
                                                           const u32* __restrict__ caV, const u32* __restrict__ ciV,
                                                           u32* __restrict__ kmax, u32* __restrict__ vmax,
                                                           float* __restrict__ kscale, float* __restrict__ vscale) {
  const int tensor = blockIdx.x;
  const u32* c = ctrl + tensor * 8;
  const u64 Kr = (((u64)c[2]) << 32) | c[3];
  u32 T = c[4];
  if (T > CAND_CAP) T = CAND_CAP;
  const u32* ca = tensor ? caV : caK;
  const u32* ci = tensor ? ciV : ciK;
  u32* mbuf = tensor ? vmax : kmax;
  for (u32 i = threadIdx.x; i < T; i += 256) {
    const u32 ab = ca[i], idx = ci[i];
    const u64 key = (((u64)ab) << 32) | (u32)(~idx);
    if (key >= Kr) continue;                              // outlier -> excluded
    if (tensor == 1 && ((idx >> 7) & 2047) < 4) continue; // V sink -> excluded
    atomicMax(&mbuf[(idx >> 18) * HD + (idx & 127)], ab);
  }
  __syncthreads();
  float* sbuf = tensor ? vscale : kscale;
  for (int i = threadIdx.x; i < NH * HD; i += 256) {
    union { u32 u; float f; } a; a.u = mbuf[i];
    sbuf[i] = fmaxf(a.f, 1e-6f) / 7.0f;
  }
}

// ---------------- K6: reconstruct K -> bf16 krec (row-major) ----------------
__global__ __launch_bounds__(256) void recon_k_kernel(const float* __restrict__ K,
                                                      const u32* __restrict__ ctrl,
                                                      const float* __restrict__ kscale,
                                                      u16* __restrict__ krec) {
  const u32 t = ctrl[0];
  const u64 Kr = (((u64)ctrl[2]) << 32) | ctrl[3];
  const int stride = gridDim.x * 256;
  for (int i = blockIdx.x * 256 + threadIdx.x; i < N_ELEM / 4; i += stride) {
    const u32 e = (u32)i * 4;
    const u32 d0 = e & 127, h = e >> 18;
    f32x4 x = *(const f32x4*)(K + e);
    f32x4 sc = *(const f32x4*)(kscale + h * HD + d0);
    u16 y[4];
#pragma unroll
    for (int j = 0; j < 4; ++j) y[j] = f2bf(dqf(x[j], t, Kr, e + j, false, sc[j]));
    *(u32*)(krec + e) = ((u32)y[0]) | (((u32)y[1]) << 16);
    *(u32*)(krec + e + 2) = ((u32)y[2]) | (((u32)y[3]) << 16);
  }
}

// ---------------- K7: reconstruct V -> bf16 vrecT, 64-token-tile transposed ---------
__global__ __launch_bounds__(256) void recon_vt_kernel(const float* __restrict__ V,
                                                       const u32* __restrict__ ctrl,
                                                       const float* __restrict__ vscale,
                                                       u16* __restrict__ vrecT) {
  __shared__ u32 ld[64][65];   // [d-pair][s_local], pad 64->65 (2-way max)
  const u32 t = ctrl[8];
  const u64 Kr = (((u64)ctrl[10]) << 32) | ctrl[11];
  const int h = blockIdx.x, sb = blockIdx.y;
  const int tid = threadIdx.x;
  const int d0 = 4 * (tid & 31);
  f32x4 sc = *(const f32x4*)(vscale + h * HD + d0);
#pragma unroll
  for (int p = 0; p < 8; ++p) {
    const int sl = p * 8 + (tid >> 5);
    const int tok = sb * 64 + sl;
    const bool sink = tok < 4;
    const u32 idx = ((u32)(h * SEQ + tok) << 7) + (u32)d0;
    f32x4 x = *(const f32x4*)(V + idx);
    u16 y[4];
#pragma unroll
    for (int j = 0; j < 4; ++j) y[j] = f2bf(dqf(x[j], t, Kr, idx + j, sink, sc[j]));
    ld[(d0 >> 1)][sl] = ((u32)y[0]) | (((u32)y[1]) << 16);
    ld[(d0 >> 1) + 1][sl] = ((u32)y[2]) | (((u32)y[3]) << 16);
  }
  __syncthreads();
  const int d = tid >> 1, so = (tid & 1) * 32, e = d & 1;
  u16* outp = vrecT + (size_t)(h * 32 + sb) * 8192 + d * 64 + so;
#pragma unroll
  for (int i = 0; i < 4; ++i) {
    short8 y;
#pragma unroll
    for (int m = 0; m < 8; ++m) {
      const u32 w2 = ld[d >> 1][so + i * 8 + m];
      y[m] = (short)(u16)(w2 >> (16 * e));
    }
    *(short8*)(outp + i * 8) = y;
  }
}

// ---------------- K8: flash attention, BM=128 paired q-tiles, pipelined -------------
// Block = head h x pair a: q-tiles {a, 31-a} (64 rows each) -> equal work (33 units).
// Register-prefetch pipeline: kt+1 K/V global loads issued before computing kt.
__global__ __launch_bounds__(256, 2) void flash_pre(const float* __restrict__ Q,
                                                    const u16* __restrict__ krec,
                                                    const u16* __restrict__ vrecT,
                                                    float* __restrict__ Out) {
  __shared__ u16 ks[64][136];     // K tile (token x channel), pad 128->136
  __shared__ u16 vt[128][72];     // V^T tile (channel x token), pad 64->72
  __shared__ u16 pl[4][16][72];   // per-wave P tile (reused for both subtiles)

  const int blk = blockIdx.x;     // 512 = 32 heads x 16 pairs
  const int h = blk >> 4;
  const int pa = blk & 15;
  const int RA = pa << 6;          // q-tile A row base (0..960)
  const int RB = (31 - pa) << 6;   // q-tile B row base (1024..1984)
  const int tid = threadIdx.x;
  const int w = tid >> 6, lane = tid & 63;
  const int l16 = lane & 15, quad = lane >> 4;
  const float SC = 0.12751743f;    // log2(e)/sqrt(128): exp2-domain softmax
  const float NEG = -30000.0f;

  // Q A-frags for both subtiles (fp32 -> bf16)
  short8 qf[2][4];
#pragma unroll
  for (int m = 0; m < 2; ++m) {
    const int R = m ? RB : RA;
    const float* qp = Q + ((size_t)(h * SEQ + R + w * 16 + l16)) * HD + quad * 8;
#pragma unroll
    for (int c = 0; c < 4; ++c) {
      f32x4 a = *(const f32x4*)(qp + c * 32);
      f32x4 b = *(const f32x4*)(qp + c * 32 + 4);
#pragma unroll
      for (int j = 0; j < 4; ++j) {
        qf[m][c][j] = (short)f2bf(a[j]);
        qf[m][c][4 + j] = (short)f2bf(b[j]);
      }
    }
  }

  f32x4 o[2][8];
  float mrow[2][4], lrow[2][4];
#pragma unroll
  for (int m = 0; m < 2; ++m) {
#pragma unroll
    for (int i = 0; i < 8; ++i) o[m][i] = (f32x4){0.f, 0.f, 0.f, 0.f};
#pragma unroll
    for (int r = 0; r < 4; ++r) { mrow[m][r] = NEG; lrow[m][r] = 0.f; }
  }

  // staging thread mapping + prefetch registers
  const int krow = tid >> 2, kqo = (tid & 3) * 32;   // K: 64 rows x 256B
  const int vd = tid >> 1, vso = (tid & 1) * 32;     // V^T: 128 rows x 128B
  const u16* kbase = krec + ((size_t)h * SEQ + krow) * HD + kqo;
  const u16* vbase = vrecT + (size_t)h * 32 * 8192 + vd * 64 + vso;
  short8 kr[4], vr[4];
#pragma unroll
  for (int i = 0; i < 4; ++i) kr[i] = *(const short8*)(kbase + i * 8);
#pragma unroll
  for (int i = 0; i < 4; ++i) vr[i] = *(const short8*)(vbase + i * 8);

  const int ktiles = (RB >> 6) + 1;   // 17..32
  for (int kt = 0; kt < ktiles; ++kt) {
    const int kb = kt << 6;
    __syncthreads();                  // previous compute done with LDS
#pragma unroll
    for (int i = 0; i < 4; ++i) *(short8*)(&ks[krow][kqo + i * 8]) = kr[i];
#pragma unroll
    for (int i = 0; i < 4; ++i) *(short8*)(&vt[vd][vso + i * 8]) = vr[i];
    __syncthreads();
    if (kt + 1 < ktiles) {            // prefetch next tile under this tile's compute
      const u16* kp = kbase + (size_t)(kt + 1) * 64 * HD;
      const u16* vp = vbase + (size_t)(kt + 1) * 8192;
#pragma unroll
      for (int i = 0; i < 4; ++i) kr[i] = *(const short8*)(kp + i * 8);
#pragma unroll
      for (int i = 0; i < 4; ++i) vr[i] = *(const short8*)(vp + i * 8);
    }
#pragma unroll
    for (int m = 0; m < 2; ++m) {
      const int R = m ? RB : RA;
      if (kb > R) continue;           // fully masked subtile
      // S = Q K^T
      f32x4 sa[4];
#pragma unroll
      for (int ni = 0; ni < 4; ++ni) {
        f32x4 acc = (f32x4){0.f, 0.f, 0.f, 0.f};
#pragma unroll
        for (int c = 0; c < 4; ++c) {
          short8 kf = *(const short8*)(&ks[ni * 16 + l16][c * 32 + quad * 8]);
          acc = __builtin_amdgcn_mfma_f32_16x16x32_bf16(qf[m][c], kf, acc, 0, 0, 0);
        }
        sa[ni] = acc;
      }
      const bool diag = (kb == R);
#pragma unroll
      for (int ni = 0; ni < 4; ++ni)
#pragma unroll
        for (int r = 0; r < 4; ++r) {
          float sv = sa[ni][r] * SC;
          if (diag && (ni * 16 + l16) > (w * 16 + quad * 4 + r)) sv = NEG;
          sa[ni][r] = sv;
        }
      // online softmax (exp2 domain), DPP row reductions
      float alpha[4];
#pragma unroll
      for (int r = 0; r < 4; ++r) {
        float mx = fmaxf(fmaxf(sa[0][r], sa[1][r]), fmaxf(sa[2][r], sa[3][r]));
        mx = rowmax16(mx);
        const float mn = fmaxf(mrow[m][r], mx);
        alpha[r] = exp2f(mrow[m][r] - mn);
        mrow[m][r] = mn;
        float sum = 0.f;
#pragma unroll
        for (int ni = 0; ni < 4; ++ni) {
          const float p = exp2f(sa[ni][r] - mn);
          sa[ni][r] = p;
          sum += p;
        }
        sum = rowsum16(sum);
        lrow[m][r] = lrow[m][r] * alpha[r] + sum;
      }
      // P (C-layout) -> per-wave LDS -> A-frags (same-wave DS ops are in-order)
#pragma unroll
      for (int ni = 0; ni < 4; ++ni)
#pragma unroll
        for (int r = 0; r < 4; ++r)
          pl[w][quad * 4 + r][ni * 16 + l16] = f2bf(sa[ni][r]);
#pragma unroll
      for (int i = 0; i < 8; ++i)
#pragma unroll
        for (int r = 0; r < 4; ++r) o[m][i][r] *= alpha[r];
      // O += P V
#pragma unroll
      for (int kc = 0; kc < 2; ++kc) {
        short8 af = *(const short8*)(&pl[w][l16][kc * 32 + quad * 8]);
#pragma unroll
        for (int ds = 0; ds < 8; ++ds) {
          short8 vf = *(const short8*)(&vt[ds * 16 + l16][kc * 32 + quad * 8]);
          o[m][ds] = __builtin_amdgcn_mfma_f32_16x16x32_bf16(af, vf, o[m][ds], 0, 0, 0);
        }
      }
    }
  }
  // epilogue
#pragma unroll
  for (int m = 0; m < 2; ++m) {
    const int R = m ? RB : RA;
#pragma unroll
    for (int r = 0; r < 4; ++r) {
      const float inv = 1.0f / lrow[m][r];
      const int qr = R + w * 16 + quad * 4 + r;
      float* op = Out + ((size_t)(h * SEQ + qr)) * HD + l16;
#pragma unroll
      for (int ds = 0; ds < 8; ++ds) op[ds * 16] = o[m][ds][r] * inv;
    }
  }
}

// ---------------- fallback flash (round-3/4 passing version, inline dequant) --------
__global__ __launch_bounds__(256, 2) void flash_fb(const float* __restrict__ Q,
                                                   const float* __restrict__ K,
                                                   const float* __restrict__ V,
                                                   const u32* __restrict__ ctrl,
                                                   const float* __restrict__ kscale,
                                                   const float* __restrict__ vscale,
                                                   float* __restrict__ Out) {
  __shared__ u16 ks[64][136];
  __shared__ u16 vt[128][72];
  __shared__ u16 pl[4][16][72];
  const int blk = blockIdx.x;
  const int h = blk >> 5;
  const int qt = 31 - (blk & 31);
  const int qb = qt << 6;
  const int tid = threadIdx.x;
  const int w = tid >> 6, lane = tid & 63;
  const int l16 = lane & 15, quad = lane >> 4;
  const float SM_SCALE = 0.08838834764831843f;
  const float NEG = -30000.0f;
  const u32 tK = ctrl[0];
  const u64 KrK = (((u64)ctrl[2]) << 32) | ctrl[3];
  const u32 tV = ctrl[8];
  const u64 KrV = (((u64)ctrl[10]) << 32) | ctrl[11];
  const int cch = (tid & 15) * 8;
  float ksc[8], vsc[8];
#pragma unroll
  for (int j = 0; j < 8; ++j) {
    ksc[j] = kscale[h * HD + cch + j];
    vsc[j] = vscale[h * HD + cch + j];
  }
  short8 qf[4];
  {
    const float* qp = Q + ((size_t)(h * SEQ + qb + w * 16 + l16)) * HD + quad * 8;
#pragma unroll
    for (int c = 0; c < 4; ++c) {
      f32x4 a = *(const f32x4*)(qp + c * 32);
      f32x4 b = *(const f32x4*)(qp + c * 32 + 4);
#pragma unroll
      for (int j = 0; j < 4; ++j) {
        qf[c][j] = (short)f2bf(a[j]);
        qf[c][4 + j] = (short)f2bf(b[j]);
      }
    }
  }
  f32x4 o[8];
#pragma unroll
  for (int i = 0; i < 8; ++i) o[i] = (f32x4){0.f, 0.f, 0.f, 0.f};
  float mrow[4], lrow[4];
#pragma unroll
  for (int r = 0; r < 4; ++r) { mrow[r] = NEG; lrow[r] = 0.f; }
  const int ktiles = qt + 1;
  for (int kt = 0; kt < ktiles; ++kt) {
    const int kb = kt << 6;
    __syncthreads();
    {
      const int r0 = tid >> 4;
      const float* kp = K + (size_t)(h * SEQ + kb) * HD;
#pragma unroll
      for (int i = 0; i < 4; ++i) {
        const int row = r0 + i * 16;
        f32x4 x0 = *(const f32x4*)(kp + (size_t)row * HD + cch);
        f32x4 x1 = *(const f32x4*)(kp + (size_t)row * HD + cch + 4);
        const u32 bidx = ((u32)(h * SEQ + kb + row) << 7) + (u32)cch;
        short8 yv;
#pragma unroll
        for (int j = 0; j < 4; ++j) {
          yv[j]     = (short)f2bf(dqf(x0[j], tK, KrK, bidx + j,     false, ksc[j]));
          yv[4 + j] = (short)f2bf(dqf(x1[j], tK, KrK, bidx + 4 + j, false, ksc[4 + j]));
        }
        *(short8*)(&ks[row][cch]) = yv;
      }
    }
    {
      const float* vp = V + (size_t)(h * SEQ + kb) * HD;
#pragma unroll
      for (int i = 0; i < 4; ++i) {
        const int tchunk = tid + i * 256;
        const int s = tchunk >> 4;
        const int tok = kb + s;
        const bool sink = tok < 4;
        f32x4 x0 = *(const f32x4*)(vp + (size_t)s * HD + cch);
        f32x4 x1 = *(const f32x4*)(vp + (size_t)s * HD + cch + 4);
        const u32 bidx = ((u32)(h * SEQ + tok) << 7) + (u32)cch;
#pragma unroll
        for (int j = 0; j < 4; ++j) {
          vt[cch + j][s]     = f2bf(dqf(x0[j], tV, KrV, bidx + j,     sink, vsc[j]));
          vt[cch + 4 + j][s] = f2bf(dqf(x1[j], tV, KrV, bidx + 4 + j, sink, vsc[4 + j]));
        }
      }
    }
    __syncthreads();
    f32x4 sa[4];
#pragma unroll
    for (int ni = 0; ni < 4; ++ni) {
      f32x4 acc = (f32x4){0.f, 0.f, 0.f, 0.f};
#pragma unroll
      for (int c = 0; c < 4; ++c) {
        short8 kf = *(const short8*)(&ks[ni * 16 + l16][c * 32 + quad * 8]);
        acc = __builtin_amdgcn_mfma_f32_16x16x32_bf16(qf[c], kf, acc, 0, 0, 0);
      }
      sa[ni] = acc;
    }
    const bool diag = (kb == qb);
#pragma unroll
    for (int ni = 0; ni < 4; ++ni)
#pragma unroll
      for (int r = 0; r < 4; ++r) {
        float sv = sa[ni][r] * SM_SCALE;
        if (diag) {
          const int qr = w * 16 + quad * 4 + r;
          const int kc = ni * 16 + l16;
          if (kc > qr) sv = NEG;
        }
        sa[ni][r] = sv;
      }
    float alpha[4];
#pragma unroll
    for (int r = 0; r < 4; ++r) {
      float mx = fmaxf(fmaxf(sa[0][r], sa[1][r]), fmaxf(sa[2][r], sa[3][r]));
      mx = fmaxf(mx, __shfl_xor(mx, 1));
      mx = fmaxf(mx, __shfl_xor(mx, 2));
      mx = fmaxf(mx, __shfl_xor(mx, 4));
      mx = fmaxf(mx, __shfl_xor(mx, 8));
      const float mn = fmaxf(mrow[r], mx);
      alpha[r] = __expf(mrow[r] - mn);
      mrow[r] = mn;
      float sum = 0.f;
#pragma unroll
      for (int ni = 0; ni < 4; ++ni) {
        const float p = __expf(sa[ni][r] - mn);
        sa[ni][r] = p;
        sum += p;
      }
      sum += __shfl_xor(sum, 1);
      sum += __shfl_xor(sum, 2);
      sum += __shfl_xor(sum, 4);
      sum += __shfl_xor(sum, 8);
      lrow[r] = lrow[r] * alpha[r] + sum;
    }
#pragma unroll
    for (int ni = 0; ni < 4; ++ni)
#pragma unroll
      for (int r = 0; r < 4; ++r)
        pl[w][quad * 4 + r][ni * 16 + l16] = f2bf(sa[ni][r]);
    __syncthreads();
#pragma unroll
    for (int i = 0; i < 8; ++i)
#pragma unroll
      for (int r = 0; r < 4; ++r) o[i][r] *= alpha[r];
#pragma unroll
    for (int kc = 0; kc < 2; ++kc) {
      short8 af = *(const short8*)(&pl[w][l16][kc * 32 + quad * 8]);
#pragma unroll
      for (int ds = 0; ds < 8; ++ds) {
        short8 vf = *(const short8*)(&vt[ds * 16 + l16][kc * 32 + quad * 8]);
        o[ds] = __builtin_amdgcn_mfma_f32_16x16x32_bf16(af, vf, o[ds], 0, 0, 0);
      }
    }
  }
#pragma unroll
  for (int r = 0; r < 4; ++r) {
    const float inv = 1.0f / lrow[r];
    const int qr = qb + w * 16 + quad * 4 + r;
    float* op = Out + ((size_t)(h * SEQ + qr)) * HD + l16;
#pragma unroll
    for (int ds = 0; ds < 8; ++ds) op[ds * 16] = o[ds][r] * inv;
  }
}

// ---------------- launcher ----------------
extern "C" void kernel_launch(void* const* d_in, const int* in_sizes, int n_in,
                              void* d_out, int out_size, void* d_ws, size_t ws_size,
                              hipStream_t stream) {
  const float* q = (const float*)d_in[0];
  const float* k = (const float*)d_in[1];
  const float* v = (const float*)d_in[2];
  float* out = (float*)d_out;
  char* ws = (char*)d_ws;

  u32* ctrl    = (u32*)ws;                               // 256 B
  u32* histK   = (u32*)(ws + 256);                       // 128 KB
  u32* histV   = (u32*)(ws + 256 + 131072);              // 128 KB
  u32* kmax    = (u32*)(ws + 262400);                    // 16 KB
  u32* vmax    = (u32*)(ws + 278784);                    // 16 KB
  const size_t ZERO_BYTES = 295168;                      // ctrl+hists+maxes
  float* kscale = (float*)(ws + 295168);                 // 16 KB
  float* vscale = (float*)(ws + 311552);                 // 16 KB
  u32* caK = (u32*)(ws + 327936);                        // 4x32 KB
  u32* ciK = caK + CAND_CAP;
  u32* caV = ciK + CAND_CAP;
  u32* ciV = caV + CAND_CAP;
  u16* krec  = (u16*)(ws + 458752);                      // 16 MB
  u16* vrecT = (u16*)(ws + 458752 + 16777216);           // 16 MB
  const size_t NEED = 458752 + 2ull * 16777216;

  hipMemsetAsync(ws, 0, ZERO_BYTES, stream);
  hist_kernel<<<256, 256, 0, stream>>>(k, v, histK, histV);
  thresh_kernel<<<2, 256, 0, stream>>>(histK, histV, ctrl);
  candmax_kernel<<<dim3(256, 2), 256, 0, stream>>>(k, v, ctrl, caK, ciK, caV, ciV, kmax, vmax);
  ksel_kernel<<<dim3(32, 2), 256, 0, stream>>>(ctrl, caK, ciK, caV, ciV);
  maxfix_scale_kernel<<<2, 256, 0, stream>>>(ctrl, caK, ciK, caV, ciV, kmax, vmax, kscale, vscale);
  if (ws_size >= NEED) {
    recon_k_kernel<<<2048, 256, 0, stream>>>(k, ctrl, kscale, krec);
    recon_vt_kernel<<<dim3(32, 32), 256, 0, stream>>>(v, ctrl, vscale, vrecT);
    flash_pre<<<512, 256, 0, stream>>>(q, krec, vrecT, out);
  } else {
    flash_fb<<<32 * 32, 256, 0, stream>>>(q, k, v, ctrl, kscale, vscale, out);
  }
}